// Round 25
// baseline (99.390 us; speedup 1.0000x reference)
//
#include <hip/hip_runtime.h>

typedef __bf16 bf16_t;
typedef __attribute__((ext_vector_type(8))) __bf16 bf16x8;
typedef __attribute__((ext_vector_type(4))) __bf16 bf16x4;
typedef __attribute__((ext_vector_type(4))) float f32x4;
typedef __attribute__((ext_vector_type(4))) short short4v;

#if __has_builtin(__builtin_amdgcn_mfma_f32_16x16x16bf16_1k)
#define HAVE_MFMA16 1
#else
#define HAVE_MFMA16 0
#endif

#if __has_builtin(__builtin_amdgcn_exp2f)
#define EXP2(x) __builtin_amdgcn_exp2f(x)
#else
#define EXP2(x) exp2f(x)
#endif

// 512-thread blocks, ONE WAVE PER HEAD (w = tid>>6 = head), (512,4).
// R25 = R21 champion body (97.4 us: 2 barriers, O in own LDS region) with a
// T15-style 2-TILE SOFTWARE PIPELINE in the attn loop: tile mt+1's QK^T MFMAs
// (+bias loads) are ISSUED before tile mt's exp2/sum/shfl/PV chain runs, so
// the matrix pipe works while the VALU chain serializes (separate pipes).
// Double st buffers (stA/stB) with static indexing (full unroll -> mt&1 is
// compile-time; rule #20). +16 regs, peak ~96 < 128 cap -> no spill.
// LDS 25600 B: Xw [0,12544), O [12544,25088), offTab [25088,25600).
// K=32 projection duality (Q,K,V,P never in LDS); exp2 softmax, log2e folded
// into Wq/bias (pad -14427 -> exact 0), bias via MFMA C-operand, post-PV
// normalization, offTab epilogue addressing.
// Rows >=49 never stored; reads clamp row->48 (garbage masked by bias/guards).
#define LDS_XW 0
#define LDS_O  12544

// ws layout: wq/wk/wv/wo K=32 B-frag packs, bf16, elements [0,65536)
//            biasPadF32[8][64][64] at byte offset 131072  => 262144 bytes total

__device__ __forceinline__ f32x4 mfma16(bf16x4 a, bf16x4 b, f32x4 c) {
#if HAVE_MFMA16
    return __builtin_amdgcn_mfma_f32_16x16x16bf16_1k(
        __builtin_bit_cast(short4v, a), __builtin_bit_cast(short4v, b), c, 0, 0, 0);
#else
    bf16x8 a8, b8;
#pragma unroll
    for (int j = 0; j < 8; ++j) { a8[j] = (bf16_t)0.0f; b8[j] = (bf16_t)0.0f; }
#pragma unroll
    for (int j = 0; j < 4; ++j) { a8[j] = a[j]; b8[j] = b[j]; }
    return __builtin_amdgcn_mfma_f32_16x16x32_bf16(a8, b8, c, 0, 0, 0);
#endif
}

__global__ void repack_kernel(const float* __restrict__ wq, const float* __restrict__ wk,
                              const float* __restrict__ wv, const float* __restrict__ wo,
                              const float* __restrict__ rel_bias, bf16_t* __restrict__ ws)
{
    const float LOG2E = 1.44269504088896f;
    int idx = blockIdx.x * 256 + threadIdx.x;
    if (idx < 65536) {
        // K=32 B-frag pack (== A-frag of W^T, same bits):
        // pack[(((ks*8 + nt)*64 + l)*8 + j)] = W[ks*32 + (l>>4)*8 + j][nt*16 + (l&15)]
        int mat = idx >> 14;
        int r = idx & 16383;
        int j = r & 7, l = (r >> 3) & 63, nt = (r >> 9) & 7, ks = r >> 12;
        int k = ks * 32 + (l >> 4) * 8 + j;
        int n = nt * 16 + (l & 15);
        const float* w = (mat == 0) ? wq : (mat == 1) ? wk : (mat == 2) ? wv : wo;
        float v = w[k * 128 + n];
        if (mat == 0) v *= 0.25f * LOG2E;    // fold q scale HS^-0.5 AND log2(e)
        ws[idx] = (bf16_t)v;
    } else if (idx < 98304) {
        // biasPadF32[h][m][n] x log2(e); padding = -14427 (exp2 -> exact 0)
        int r = idx - 65536;
        int h = r >> 12, m = (r >> 6) & 63, n = r & 63;
        float v = -14427.0f;
        if (m < 49 && n < 49) {
            int im = m / 7, jm = m % 7, in_ = n / 7, jn = n % 7;
            v = rel_bias[((im - in_ + 6) * 13 + (jm - jn + 6)) * 8 + h] * LOG2E;
        }
        ((float*)(ws + 65536))[r] = v;       // f32 bias (feeds MFMA C directly)
    }
}

__global__ __launch_bounds__(512, 4)
void win_attn_kernel(const float* __restrict__ x, const float* __restrict__ b_o,
                     const bf16_t* __restrict__ wpack, float* __restrict__ out)
{
    __shared__ __align__(16) unsigned char smem[25600];
    int* offTab = (int*)(smem + 25088);          // [64] window-row -> global row offset
    const float* biasT = (const float*)(wpack + 65536);
    const int tid = threadIdx.x;
    const int blk = blockIdx.x;                  // 4096 windows: b*256 + wh*16 + ww
    const int b  = blk >> 8;
    const int wh = (blk >> 4) & 15;
    const int ww = blk & 15;
    const int w  = tid >> 6;                     // wave 0..7 == head
    const int lane = tid & 63;
    const int c  = lane & 15;
    const int hi = lane >> 4;                    // 0..3
    const f32x4 fzero = {0.f, 0.f, 0.f, 0.f};

    // ---------------- offset table + stage x window -> Xw [49][128] bf16 ----------------
    if (tid < 64) {
        int mm = (tid < 49) ? tid : 48;
        int i = mm / 7, j = mm - 7 * i;
        offTab[tid] = ((b * 112 + wh * 7 + i) * 112 + ww * 7 + j) * 128;
    }
#pragma unroll
    for (int it = 0; it < 4; ++it) {
        int idx = tid + it * 512;                // need 1568 = 49 rows * 32 float4
        if (idx < 1568) {
            int m  = idx >> 5;                   // 0..48
            int c4 = idx & 31;
            int i = m / 7, j = m - 7 * i;
            float4 v = *(const float4*)(x + ((b * 112 + wh * 7 + i) * 112 + ww * 7 + j) * 128 + c4 * 4);
            bf16x4 bv;
            bv[0] = (bf16_t)v.x; bv[1] = (bf16_t)v.y; bv[2] = (bf16_t)v.z; bv[3] = (bf16_t)v.w;
            int ch = (c4 >> 1) ^ (m & 7);        // 16B-chunk XOR swizzle
            *(bf16x4*)(smem + LDS_XW + m * 256 + ch * 16 + (c4 & 1) * 8) = bv;
        }
    }
    __syncthreads();                             // barrier A: Xw + offTab ready

    // ---------------- projections (K=32 MFMA), single pass, head slice ----------------
    // qreg/kreg[nt]: {Q,K}[tok = nt*16+c][ch = 16w + 4hi+j]
    // vreg[nt]:      V[tok = nt*16+4hi+j][d = 16w + c]
    bf16x4 qreg[4], kreg[4], vreg[4];
#pragma unroll
    for (int nt = 0; nt < 4; ++nt) {
        int row = nt * 16 + c;
        int rowc = (row < 49) ? row : 48;        // clamp (garbage masked downstream)
        const unsigned char* xbase = smem + LDS_XW + rowc * 256;
        int rsw = rowc & 7;
        bf16x8 xf[4];                            // Xw A-frag == X^T B-frag, same bits
#pragma unroll
        for (int ks = 0; ks < 4; ++ks)
            xf[ks] = *(const bf16x8*)(xbase + (((4 * ks + hi) ^ rsw) << 4));
        f32x4 aq = fzero, ak = fzero, av = fzero;
#pragma unroll
        for (int ks = 0; ks < 4; ++ks) {
            bf16x8 w0 = *(const bf16x8*)(wpack + 0 * 16384 + ((ks * 8 + w) * 64 + lane) * 8);
            bf16x8 w1 = *(const bf16x8*)(wpack + 1 * 16384 + ((ks * 8 + w) * 64 + lane) * 8);
            bf16x8 w2 = *(const bf16x8*)(wpack + 2 * 16384 + ((ks * 8 + w) * 64 + lane) * 8);
            aq = __builtin_amdgcn_mfma_f32_16x16x32_bf16(w0, xf[ks], aq, 0, 0, 0);
            ak = __builtin_amdgcn_mfma_f32_16x16x32_bf16(w1, xf[ks], ak, 0, 0, 0);
            av = __builtin_amdgcn_mfma_f32_16x16x32_bf16(xf[ks], w2, av, 0, 0, 0);
        }
        bf16x4 q, k, vv;
#pragma unroll
        for (int r = 0; r < 4; ++r) {
            q[r]  = (bf16_t)aq[r];
            k[r]  = (bf16_t)ak[r];
            vv[r] = (bf16_t)av[r];
        }
        qreg[nt] = q; kreg[nt] = k; vreg[nt] = vv;
    }
    // NO barrier: O has its own region; each wave proceeds straight to attn.

    // ---------------- attn: 2-tile pipeline (issue QK^T[mt+1] ∥ softmax/PV[mt]) ----------------
    const int col = 16 * w + c;                  // O column, fixed per thread
    const int colhi = col >> 3;
    const int collo = (col & 7) * 2;
    int chO[4];
#pragma unroll
    for (int r = 0; r < 4; ++r)                  // mt-invariant: row&7 == (4hi+r)&7
        chO[r] = (colhi ^ ((4 * hi + r) & 7)) * 16 + collo;

    f32x4 stA[4], stB[4];                        // double S^T buffers (static idx)
#pragma unroll
    for (int nt = 0; nt < 4; ++nt) {             // prologue: tile 0 QK^T
        f32x4 bb = *(const f32x4*)(biasT + (w * 64 + c) * 64 + nt * 16 + 4 * hi);
        stA[nt] = mfma16(kreg[nt], qreg[0], bb);
    }
#pragma unroll
    for (int mt = 0; mt < 4; ++mt) {             // fully unrolled: mt&1 compile-time
        f32x4 (&stC)[4] = (mt & 1) ? stB : stA;  // current tile's S^T
        f32x4 (&stN)[4] = (mt & 1) ? stA : stB;  // next tile's S^T
        if (mt < 3) {                            // ISSUE next tile's QK^T first
            int m2 = (mt + 1) * 16 + c;
#pragma unroll
            for (int nt = 0; nt < 4; ++nt) {
                f32x4 bb = *(const f32x4*)(biasT + (w * 64 + m2) * 64 + nt * 16 + 4 * hi);
                stN[nt] = mfma16(kreg[nt], qreg[mt + 1], bb);
            }
        }
        // ... while this tile's serial VALU chain runs (overlaps on MFMA pipe)
        float sum = 0.f;
#pragma unroll
        for (int nt = 0; nt < 4; ++nt)
#pragma unroll
            for (int r = 0; r < 4; ++r) {
                float p = EXP2(stC[nt][r]);
                stC[nt][r] = p;
                sum += p;
            }
        sum += __shfl_xor(sum, 16);
        sum += __shfl_xor(sum, 32);
        float inv = 1.f / sum;                   // per lane: inv for q-tok = c
        f32x4 oacc = fzero;                      // fused PV on UNNORMALIZED P
#pragma unroll
        for (int nt = 0; nt < 4; ++nt) {
            bf16x4 pv;
#pragma unroll
            for (int r = 0; r < 4; ++r) pv[r] = (bf16_t)stC[nt][r];
            oacc = mfma16(pv, vreg[nt], oacc);
        }
        // O (bf16, [49][256B]) own region; normalize here (inv at lane 4hi+r)
#pragma unroll
        for (int r = 0; r < 4; ++r) {
            float invr = __shfl(inv, 4 * hi + r);
            int row = mt * 16 + hi * 4 + r;
            if (row < 49)
                *(bf16_t*)(smem + LDS_O + row * 256 + chO[r]) = (bf16_t)(oacc[r] * invr);
        }
    }
    // Wo frags + bias loaded here (latency may hide under other waves' attn)
    bf16x8 wof[4];
#pragma unroll
    for (int ks = 0; ks < 4; ++ks)
        wof[ks] = *(const bf16x8*)(wpack + 3 * 16384 + ((ks * 8 + w) * 64 + lane) * 8);
    float bb = b_o[col];
    __syncthreads();                             // barrier C: O complete from all waves

    // ---------------- output projection + b_o, wave w -> out cols [16w,16w+16) ----------------
#pragma unroll
    for (int mt = 0; mt < 4; ++mt) {
        int row = mt * 16 + c;
        int rowc = (row < 49) ? row : 48;        // clamp into 49-row O
        int rsw = rowc & 7;
        f32x4 acc = fzero;
#pragma unroll
        for (int ks = 0; ks < 4; ++ks) {
            bf16x8 a = *(const bf16x8*)(smem + LDS_O + rowc * 256 + (((4 * ks + hi) ^ rsw) << 4));
            acc = __builtin_amdgcn_mfma_f32_16x16x32_bf16(a, wof[ks], acc, 0, 0, 0);
        }
        int4 o4 = *(const int4*)(offTab + mt * 16 + 4 * hi);   // one b128: rows 4hi..4hi+3
        int offv[4] = {o4.x, o4.y, o4.z, o4.w};
#pragma unroll
        for (int r = 0; r < 4; ++r) {
            int m = mt * 16 + hi * 4 + r;
            if (m < 49)
                out[offv[r] + col] = acc[r] + bb;
        }
    }
}

extern "C" void kernel_launch(void* const* d_in, const int* in_sizes, int n_in,
                              void* d_out, int out_size, void* d_ws, size_t ws_size,
                              hipStream_t stream) {
    const float* x   = (const float*)d_in[0];
    const float* wq  = (const float*)d_in[1];
    const float* wk  = (const float*)d_in[2];
    const float* wvp = (const float*)d_in[3];
    const float* wo  = (const float*)d_in[4];
    const float* bo  = (const float*)d_in[5];
    const float* rb  = (const float*)d_in[6];
    bf16_t* wpack = (bf16_t*)d_ws;               // needs 262144 bytes of ws

    repack_kernel<<<384, 256, 0, stream>>>(wq, wk, wvp, wo, rb, wpack);
    win_attn_kernel<<<4096, 512, 0, stream>>>(x, bo, wpack, (float*)d_out);
}

// Round 26
// 97.327 us; speedup vs baseline: 1.0212x; 1.0212x over previous
//
#include <hip/hip_runtime.h>

typedef __bf16 bf16_t;
typedef __attribute__((ext_vector_type(8))) __bf16 bf16x8;
typedef __attribute__((ext_vector_type(4))) __bf16 bf16x4;
typedef __attribute__((ext_vector_type(4))) float f32x4;
typedef __attribute__((ext_vector_type(4))) short short4v;

#if __has_builtin(__builtin_amdgcn_mfma_f32_16x16x16bf16_1k)
#define HAVE_MFMA16 1
#else
#define HAVE_MFMA16 0
#endif

#if __has_builtin(__builtin_amdgcn_exp2f)
#define EXP2(x) __builtin_amdgcn_exp2f(x)
#else
#define EXP2(x) exp2f(x)
#endif

// FINAL (champion, R21 body, 97.37 us): 512-thread blocks, ONE WAVE PER HEAD
// (w = tid>>6), __launch_bounds__(512,4) — the proven no-spill sweet spot
// (>4 waves/EU spills the unified arch+acc register budget; 3/3 attempts).
// Structure:
//  - 2 barriers only: A (Xw+offTab staged), C (O complete). O lives in its
//    own LDS region so proj->attn needs no sync (waves write disjoint cols).
//  - K=32 projection duality: Q^T/K^T = W^T*X^T and V = X*Wv via
//    mfma_f32_16x16x32_bf16; the B-frag weight pack IS the W^T A-frag, the
//    Xw A-frag read IS the X^T B-frag, and C-outputs land bit-exactly in the
//    QK^T / PV K=16 fragment layouts. Q,K,V,P never touch LDS.
//  - exp2 softmax, log2(e) folded into Wq scale and bias table (pad -14427
//    -> exp2 == exact 0 doubles as the n>=49 mask); bias enters as the QK^T
//    MFMA C-operand; no max-subtraction (logits structurally tiny).
//  - post-PV normalization (PV consumes unnormalized P; 1/sum applied to
//    oacc via 4 shfl+mul), offTab LDS table kills div-by-7 epilogue math.
// LDS 25600 B: Xw [0,12544), O [12544,25088), offTab [25088,25600).
// Rows >=49 never stored; reads clamp row->48 (garbage masked by bias/guards).
#define LDS_XW 0
#define LDS_O  12544

// ws layout: wq/wk/wv/wo K=32 B-frag packs, bf16, elements [0,65536)
//            biasPadF32[8][64][64] at byte offset 131072  => 262144 bytes total

__device__ __forceinline__ f32x4 mfma16(bf16x4 a, bf16x4 b, f32x4 c) {
#if HAVE_MFMA16
    return __builtin_amdgcn_mfma_f32_16x16x16bf16_1k(
        __builtin_bit_cast(short4v, a), __builtin_bit_cast(short4v, b), c, 0, 0, 0);
#else
    bf16x8 a8, b8;
#pragma unroll
    for (int j = 0; j < 8; ++j) { a8[j] = (bf16_t)0.0f; b8[j] = (bf16_t)0.0f; }
#pragma unroll
    for (int j = 0; j < 4; ++j) { a8[j] = a[j]; b8[j] = b[j]; }
    return __builtin_amdgcn_mfma_f32_16x16x32_bf16(a8, b8, c, 0, 0, 0);
#endif
}

__global__ void repack_kernel(const float* __restrict__ wq, const float* __restrict__ wk,
                              const float* __restrict__ wv, const float* __restrict__ wo,
                              const float* __restrict__ rel_bias, bf16_t* __restrict__ ws)
{
    const float LOG2E = 1.44269504088896f;
    int idx = blockIdx.x * 256 + threadIdx.x;
    if (idx < 65536) {
        // K=32 B-frag pack (== A-frag of W^T, same bits):
        // pack[(((ks*8 + nt)*64 + l)*8 + j)] = W[ks*32 + (l>>4)*8 + j][nt*16 + (l&15)]
        int mat = idx >> 14;
        int r = idx & 16383;
        int j = r & 7, l = (r >> 3) & 63, nt = (r >> 9) & 7, ks = r >> 12;
        int k = ks * 32 + (l >> 4) * 8 + j;
        int n = nt * 16 + (l & 15);
        const float* w = (mat == 0) ? wq : (mat == 1) ? wk : (mat == 2) ? wv : wo;
        float v = w[k * 128 + n];
        if (mat == 0) v *= 0.25f * LOG2E;    // fold q scale HS^-0.5 AND log2(e)
        ws[idx] = (bf16_t)v;
    } else if (idx < 98304) {
        // biasPadF32[h][m][n] x log2(e); padding = -14427 (exp2 -> exact 0)
        int r = idx - 65536;
        int h = r >> 12, m = (r >> 6) & 63, n = r & 63;
        float v = -14427.0f;
        if (m < 49 && n < 49) {
            int im = m / 7, jm = m % 7, in_ = n / 7, jn = n % 7;
            v = rel_bias[((im - in_ + 6) * 13 + (jm - jn + 6)) * 8 + h] * LOG2E;
        }
        ((float*)(ws + 65536))[r] = v;       // f32 bias (feeds MFMA C directly)
    }
}

__global__ __launch_bounds__(512, 4)
void win_attn_kernel(const float* __restrict__ x, const float* __restrict__ b_o,
                     const bf16_t* __restrict__ wpack, float* __restrict__ out)
{
    __shared__ __align__(16) unsigned char smem[25600];
    int* offTab = (int*)(smem + 25088);          // [64] window-row -> global row offset
    const float* biasT = (const float*)(wpack + 65536);
    const int tid = threadIdx.x;
    const int blk = blockIdx.x;                  // 4096 windows: b*256 + wh*16 + ww
    const int b  = blk >> 8;
    const int wh = (blk >> 4) & 15;
    const int ww = blk & 15;
    const int w  = tid >> 6;                     // wave 0..7 == head
    const int lane = tid & 63;
    const int c  = lane & 15;
    const int hi = lane >> 4;                    // 0..3
    const f32x4 fzero = {0.f, 0.f, 0.f, 0.f};

    // ---------------- offset table + stage x window -> Xw [49][128] bf16 ----------------
    if (tid < 64) {
        int mm = (tid < 49) ? tid : 48;
        int i = mm / 7, j = mm - 7 * i;
        offTab[tid] = ((b * 112 + wh * 7 + i) * 112 + ww * 7 + j) * 128;
    }
#pragma unroll
    for (int it = 0; it < 4; ++it) {
        int idx = tid + it * 512;                // need 1568 = 49 rows * 32 float4
        if (idx < 1568) {
            int m  = idx >> 5;                   // 0..48
            int c4 = idx & 31;
            int i = m / 7, j = m - 7 * i;
            float4 v = *(const float4*)(x + ((b * 112 + wh * 7 + i) * 112 + ww * 7 + j) * 128 + c4 * 4);
            bf16x4 bv;
            bv[0] = (bf16_t)v.x; bv[1] = (bf16_t)v.y; bv[2] = (bf16_t)v.z; bv[3] = (bf16_t)v.w;
            int ch = (c4 >> 1) ^ (m & 7);        // 16B-chunk XOR swizzle
            *(bf16x4*)(smem + LDS_XW + m * 256 + ch * 16 + (c4 & 1) * 8) = bv;
        }
    }
    __syncthreads();                             // barrier A: Xw + offTab ready

    // ---------------- projections (K=32 MFMA), single pass, head slice ----------------
    // qreg/kreg[nt]: {Q,K}[tok = nt*16+c][ch = 16w + 4hi+j]
    // vreg[nt]:      V[tok = nt*16+4hi+j][d = 16w + c]
    bf16x4 qreg[4], kreg[4], vreg[4];
#pragma unroll
    for (int nt = 0; nt < 4; ++nt) {
        int row = nt * 16 + c;
        int rowc = (row < 49) ? row : 48;        // clamp (garbage masked downstream)
        const unsigned char* xbase = smem + LDS_XW + rowc * 256;
        int rsw = rowc & 7;
        bf16x8 xf[4];                            // Xw A-frag == X^T B-frag, same bits
#pragma unroll
        for (int ks = 0; ks < 4; ++ks)
            xf[ks] = *(const bf16x8*)(xbase + (((4 * ks + hi) ^ rsw) << 4));
        f32x4 aq = fzero, ak = fzero, av = fzero;
#pragma unroll
        for (int ks = 0; ks < 4; ++ks) {
            bf16x8 w0 = *(const bf16x8*)(wpack + 0 * 16384 + ((ks * 8 + w) * 64 + lane) * 8);
            bf16x8 w1 = *(const bf16x8*)(wpack + 1 * 16384 + ((ks * 8 + w) * 64 + lane) * 8);
            bf16x8 w2 = *(const bf16x8*)(wpack + 2 * 16384 + ((ks * 8 + w) * 64 + lane) * 8);
            aq = __builtin_amdgcn_mfma_f32_16x16x32_bf16(w0, xf[ks], aq, 0, 0, 0);
            ak = __builtin_amdgcn_mfma_f32_16x16x32_bf16(w1, xf[ks], ak, 0, 0, 0);
            av = __builtin_amdgcn_mfma_f32_16x16x32_bf16(xf[ks], w2, av, 0, 0, 0);
        }
        bf16x4 q, k, vv;
#pragma unroll
        for (int r = 0; r < 4; ++r) {
            q[r]  = (bf16_t)aq[r];
            k[r]  = (bf16_t)ak[r];
            vv[r] = (bf16_t)av[r];
        }
        qreg[nt] = q; kreg[nt] = k; vreg[nt] = vv;
    }
    // NO barrier: O has its own region; each wave proceeds straight to attn.

    // ---------------- S^T (bias in C) -> exp2/sum -> fused PV -> O ----------------
    const int col = 16 * w + c;                  // O column, fixed per thread
    const int colhi = col >> 3;
    const int collo = (col & 7) * 2;
    int chO[4];
#pragma unroll
    for (int r = 0; r < 4; ++r)                  // mt-invariant: row&7 == (4hi+r)&7
        chO[r] = (colhi ^ ((4 * hi + r) & 7)) * 16 + collo;
#pragma unroll
    for (int mt = 0; mt < 4; ++mt) {             // q-token tile
        int m = mt * 16 + c;
        f32x4 st[4];                             // S^T: col=q-tok=c, row=k-tok=nt*16+4hi+r
#pragma unroll
        for (int nt = 0; nt < 4; ++nt) {
            f32x4 bb = *(const f32x4*)(biasT + (w * 64 + m) * 64 + nt * 16 + 4 * hi);
            st[nt] = mfma16(kreg[nt], qreg[mt], bb);   // bias (x log2e) via C-operand
        }
        // softmax: hw exp2 (log2e pre-folded), no max-subtraction (logits tiny;
        // -14427 pad -> exp2 = exact 0)
        float sum = 0.f;
#pragma unroll
        for (int nt = 0; nt < 4; ++nt)
#pragma unroll
            for (int r = 0; r < 4; ++r) {
                float p = EXP2(st[nt][r]);
                st[nt][r] = p;
                sum += p;
            }
        sum += __shfl_xor(sum, 16);
        sum += __shfl_xor(sum, 32);
        float inv = 1.f / sum;                   // per lane: inv for q-tok = c
        f32x4 oacc = fzero;                      // fused PV on UNNORMALIZED P
#pragma unroll
        for (int nt = 0; nt < 4; ++nt) {
            bf16x4 pv;
#pragma unroll
            for (int r = 0; r < 4; ++r) pv[r] = (bf16_t)st[nt][r];
            oacc = mfma16(pv, vreg[nt], oacc);
        }
        // O (bf16, [49][256B]) own region; normalize here (inv at lane 4hi+r)
#pragma unroll
        for (int r = 0; r < 4; ++r) {
            float invr = __shfl(inv, 4 * hi + r);
            int row = mt * 16 + hi * 4 + r;
            if (row < 49)
                *(bf16_t*)(smem + LDS_O + row * 256 + chO[r]) = (bf16_t)(oacc[r] * invr);
        }
    }
    __syncthreads();                             // barrier C: O complete from all waves

    // ---------------- output projection + b_o, wave w -> out cols [16w,16w+16) ----------------
    float bb = b_o[col];
#pragma unroll
    for (int mt = 0; mt < 4; ++mt) {
        int row = mt * 16 + c;
        int rowc = (row < 49) ? row : 48;        // clamp into 49-row O
        int rsw = rowc & 7;
        f32x4 acc = fzero;
#pragma unroll
        for (int ks = 0; ks < 4; ++ks) {         // lazy Wo loads
            bf16x8 a  = *(const bf16x8*)(smem + LDS_O + rowc * 256 + (((4 * ks + hi) ^ rsw) << 4));
            bf16x8 w0 = *(const bf16x8*)(wpack + 3 * 16384 + ((ks * 8 + w) * 64 + lane) * 8);
            acc = __builtin_amdgcn_mfma_f32_16x16x32_bf16(a, w0, acc, 0, 0, 0);
        }
        int4 o4 = *(const int4*)(offTab + mt * 16 + 4 * hi);   // one b128: rows 4hi..4hi+3
        int offv[4] = {o4.x, o4.y, o4.z, o4.w};
#pragma unroll
        for (int r = 0; r < 4; ++r) {
            int m = mt * 16 + hi * 4 + r;
            if (m < 49)
                out[offv[r] + col] = acc[r] + bb;
        }
    }
}

extern "C" void kernel_launch(void* const* d_in, const int* in_sizes, int n_in,
                              void* d_out, int out_size, void* d_ws, size_t ws_size,
                              hipStream_t stream) {
    const float* x   = (const float*)d_in[0];
    const float* wq  = (const float*)d_in[1];
    const float* wk  = (const float*)d_in[2];
    const float* wvp = (const float*)d_in[3];
    const float* wo  = (const float*)d_in[4];
    const float* bo  = (const float*)d_in[5];
    const float* rb  = (const float*)d_in[6];
    bf16_t* wpack = (bf16_t*)d_ws;               // needs 262144 bytes of ws

    repack_kernel<<<384, 256, 0, stream>>>(wq, wk, wvp, wo, rb, wpack);
    win_attn_kernel<<<4096, 512, 0, stream>>>(x, bo, wpack, (float*)d_out);
}